// Round 5
// baseline (1023.636 us; speedup 1.0000x reference)
//
#include <hip/hip_runtime.h>
#include <hip/hip_bf16.h>

// FlowAttention: B=4 S=4096 D=1024 H=16 dk=dv=64. Inputs/outputs fp32.
// Round-10: AF32 gemm rebuilt to the proven m97 footprint.
//  - BK=64 restored (R4's BK=32 doubled barrier count: 93->138us regression).
//  - A staging for fp32 inputs: reg-staged conversion (global fp32 -> f2b -> swizzled
//    ds_write_b128 bf16). A-LDS is bf16 [128][64]; inner loop identical to bf16 path
//    (no v_cvt on the ds_read->MFMA critical path). LDS total 32KB both paths.
//  - XCD swizzle kept (R4 proved FETCH 264->49MB).
//  - colsum1 stays fused in Q/K gemm epilogue; dots1+colsum2 fused (R4, passed).
// Phase order (race-audited, unchanged from R4):
//   memset sums; P1: Q->dout[0,32), K->dout[32,64) (epilogue colsums); WV^T stays
//   stats: dots1_k, dots2(dots_k), softmax(in-place)
//   P2 per b: V_b->ws (AF32 gemm); memset kvb; kv_k; ctx_b overwrites dead K_b
//   WF^T; P3 per b: O_b = ctx_b@Wfc -> ws slot; LN -> dout fp32 rows of b
#define S_LEN 4096
#define DMODEL 1024
#define NHEAD 16
#define NROWS 16384      // B*S
#define BROWS 4096       // rows per batch
#define KV_SPLIT 16

typedef __bf16 bf16x8 __attribute__((ext_vector_type(8)));
typedef float  f32x4  __attribute__((ext_vector_type(4)));

__device__ __forceinline__ float b2f(ushort u) {
    union { uint i; float f; } c; c.i = ((uint)u) << 16; return c.f;
}
__device__ __forceinline__ float blo(uint u) {
    union { uint i; float f; } c; c.i = u << 16; return c.f;
}
__device__ __forceinline__ float bhi(uint u) {
    union { uint i; float f; } c; c.i = u & 0xFFFF0000u; return c.f;
}
__device__ __forceinline__ ushort f2b(float f) {
    union { uint i; float f; } c; c.f = f;
    uint r = c.i + 0x7FFF + ((c.i >> 16) & 1);   // round-to-nearest-even
    return (ushort)(r >> 16);
}
__device__ __forceinline__ uint pk2(float a, float b) {
    return (uint)f2b(a) | ((uint)f2b(b) << 16);
}
__device__ __forceinline__ float sigmoidf_(float x) {
    return 1.f / (1.f + __expf(-x));
}

// async 16B global->LDS DMA. Dest must be thread-linear (base + tid*16).
__device__ __forceinline__ void gld_lds16(void* lds, const void* g) {
    __builtin_amdgcn_global_load_lds(
        (const __attribute__((address_space(1))) uint*)g,
        (__attribute__((address_space(3))) uint*)lds, 16, 0, 0);
}

// ---------------- transpose 1024x1024: out[n][k] = bf16(in[k][n]), in fp32 ------
__global__ void transpose_k(const float* __restrict__ in, ushort* __restrict__ out) {
    __shared__ ushort tile[32][33];
    int x = blockIdx.x * 32 + threadIdx.x;
    int y0 = blockIdx.y * 32;
    for (int i = threadIdx.y; i < 32; i += 8)
        tile[i][threadIdx.x] = f2b(in[(size_t)(y0 + i) * DMODEL + x]);
    __syncthreads();
    int xo = blockIdx.y * 32 + threadIdx.x;
    int yo0 = blockIdx.x * 32;
    for (int i = threadIdx.y; i < 32; i += 8)
        out[(size_t)(yo0 + i) * DMODEL + xo] = tile[threadIdx.x][i];
}

// ---------------- MFMA GEMM: C[M,1024] = act(A[M,1024] @ Bt^T) ------------------
// 128x128 tile, 4 waves 2x2, each wave 64x64 via 4x4 mfma 16x16x32 bf16. BK=64.
// LDS (32KB both paths): B bf16 [128][64] @0, A bf16 [128][64] @16K.
// Swizzle byte_in_row ^= (row&7)<<4 on both tiles:
//   B: gld_lds (linear dest) + inverse-swizzled GLOBAL source (rule #21).
//   A-AF32: reg-staged (global fp32 -> f2b -> ds_write_b128 at swizzled offset).
//   A-bf16: gld_lds + inverse-swizzled source.
// Inner loop identical for both paths (pure bf16 ds_read_b128 -> MFMA).
// XCD swizzle: lid=(bid&7)*(nwg/8)+bid/8 (nwg divisible by 8; gridDim.x==8).
// csum != nullptr: epilogue per-column sums of stored output into csum[b][h][64].
template<int AF32>
__global__ __launch_bounds__(256) void gemm128(const void* __restrict__ A, size_t aoff,
                                               const ushort* __restrict__ Bt,
                                               ushort* __restrict__ C, int act,
                                               float* __restrict__ csum) {
    __shared__ __align__(16) char smem[32768];
    char* smA = smem + 16384;

    int nwg = (int)(gridDim.x * gridDim.y);
    int bid = (int)(blockIdx.y * gridDim.x + blockIdx.x);
    int lid = (bid & 7) * (nwg >> 3) + (bid >> 3);
    int n0 = (lid & 7) * 128;                     // gridDim.x == 8
    int m0 = (lid >> 3) * 128;

    int t = threadIdx.x;
    int lane = t & 63, wave = t >> 6;
    int wm = (wave >> 1) * 64, wn = (wave & 1) * 64;
    int fr = lane & 15;            // frag row (A) / col (B)
    int kq = (lane >> 4) * 8;      // k offset within 32-step

    const float*  Af = (const float*)A + aoff;
    const ushort* Ab = (const ushort*)A + aoff;

    // staging descriptors (k0-invariant)
    int ldsOff[4], rowOf[4], bcB[4];               // gld_lds rounds (B, and A-bf16)
    #pragma unroll
    for (int r = 0; r < 4; ++r) {
        int o = t * 16 + r * 4096;
        int row = o >> 7;
        ldsOff[r] = o;
        rowOf[r] = row;
        bcB[r] = (o & 127) ^ ((row & 7) << 4);
    }
    // A-AF32 reg-stage: thread t covers row=t>>1, k in [akh, akh+32)
    int arow = t >> 1;
    int akh = (t & 1) * 32;
    const float* aptr = Af + (size_t)(m0 + arow) * DMODEL + akh;
    int awb[4];                                    // swizzled ds_write byte offsets
    #pragma unroll
    for (int j = 0; j < 4; ++j)
        awb[j] = ((arow << 7) + akh * 2 + j * 16) ^ ((arow & 7) << 4);

    f32x4 acc[4][4];
    #pragma unroll
    for (int i = 0; i < 4; ++i)
        #pragma unroll
        for (int j = 0; j < 4; ++j) acc[i][j] = (f32x4){0.f, 0.f, 0.f, 0.f};

    for (int k0 = 0; k0 < DMODEL; k0 += 64) {
        __syncthreads();   // prev iteration's LDS reads done before overwrite
        // B tile: 4 async DMA rounds (issued first; runs during A conversion)
        #pragma unroll
        for (int r = 0; r < 4; ++r)
            gld_lds16(smem + ldsOff[r],
                      Bt + (size_t)(n0 + rowOf[r]) * DMODEL + k0 + (bcB[r] >> 1));
        if (AF32) {
            // A: 8x global f32x4 -> pack bf16 -> 4x swizzled ds_write_b128
            float4 q[8];
            #pragma unroll
            for (int j = 0; j < 8; ++j)
                q[j] = *(const float4*)(aptr + k0 + j * 4);
            #pragma unroll
            for (int j = 0; j < 4; ++j) {
                uint4 wv;
                wv.x = pk2(q[2 * j].x,     q[2 * j].y);
                wv.y = pk2(q[2 * j].z,     q[2 * j].w);
                wv.z = pk2(q[2 * j + 1].x, q[2 * j + 1].y);
                wv.w = pk2(q[2 * j + 1].z, q[2 * j + 1].w);
                *(uint4*)(smA + awb[j]) = wv;
            }
        } else {
            #pragma unroll
            for (int r = 0; r < 4; ++r)
                gld_lds16(smA + ldsOff[r],
                          Ab + (size_t)(m0 + rowOf[r]) * DMODEL + k0 + (bcB[r] >> 1));
        }
        __syncthreads();   // drains DMA (vmcnt) + ds_writes (lgkmcnt)

        #pragma unroll
        for (int h = 0; h < 2; ++h) {
            bf16x8 av[4], bv[4];
            #pragma unroll
            for (int i = 0; i < 4; ++i) {
                int row = wm + i * 16 + fr;
                int k = h * 32 + kq;
                int o = ((row << 7) + (k << 1)) ^ ((row & 7) << 4);
                av[i] = *(const bf16x8*)(smA + o);
            }
            #pragma unroll
            for (int j = 0; j < 4; ++j) {
                int nrow = wn + j * 16 + fr;
                int k = h * 32 + kq;
                int o = ((nrow << 7) + (k << 1)) ^ ((nrow & 7) << 4);
                bv[j] = *(const bf16x8*)(smem + o);
            }
            #pragma unroll
            for (int i = 0; i < 4; ++i)
                #pragma unroll
                for (int j = 0; j < 4; ++j)
                    acc[i][j] = __builtin_amdgcn_mfma_f32_16x16x32_bf16(av[i], bv[j], acc[i][j], 0, 0, 0);
        }
    }

    int rbase = (lane >> 4) * 4;
    int cix = lane & 15;
    float colacc[4] = {0.f, 0.f, 0.f, 0.f};
    #pragma unroll
    for (int i = 0; i < 4; ++i)
        #pragma unroll
        for (int j = 0; j < 4; ++j) {
            int col = n0 + wn + j * 16 + cix;
            #pragma unroll
            for (int r = 0; r < 4; ++r) {
                int row = m0 + wm + i * 16 + rbase + r;
                float v = acc[i][j][r];
                if (act) v = sigmoidf_(v);
                ushort ub = f2b(v);
                C[(size_t)row * DMODEL + col] = ub;
                if (csum) colacc[j] += b2f(ub);
            }
        }
    if (csum) {
        __syncthreads();                // all LDS frag reads done; reuse smem
        float* cred = (float*)smem;     // [2][128]
        cred[t] = 0.f;
        __syncthreads();
        #pragma unroll
        for (int j = 0; j < 4; ++j) {
            float s = colacc[j];
            s += __shfl_xor(s, 16);
            s += __shfl_xor(s, 32);     // sum over wave's 64 rows
            if (lane < 16) cred[(wm >> 6) * 128 + wn + j * 16 + lane] = s;
        }
        __syncthreads();
        if (t < 128) {
            float tot = cred[t] + cred[128 + t];
            int col = n0 + t;
            int b = m0 >> 12;           // 4096 rows per batch
            atomicAdd(&csum[((size_t)b * NHEAD + (col >> 6)) * 64 + (col & 63)], tot);
        }
    }
}

// ---- fused dots1 + weighted colsum2, batched over b (z) ----
// dq = Q[s]·Ksum -> si = 1/dq (stored); dk = K[s]·Qsum -> so = 1/dk (not stored)
// QsI[d] += sum_s Q[s,d]*si[s] ; KsO[d] += sum_s K[s,d]*so[s]  (atomic per wave-lane)
__global__ void dots1_k(const ushort* __restrict__ Q, const ushort* __restrict__ K,
                        const float* __restrict__ Qsum, const float* __restrict__ Ksum,
                        float* __restrict__ si_out, float* __restrict__ qsi,
                        float* __restrict__ kso) {
    int h = blockIdx.x, b = blockIdx.z;
    int lane = threadIdx.x & 63, wv = threadIdx.x >> 6;
    const ushort* qp = Q + (size_t)b * BROWS * DMODEL + h * 64 + lane;
    const ushort* kp = K + (size_t)b * BROWS * DMODEL + h * 64 + lane;
    float vql = Ksum[((size_t)b * NHEAD + h) * 64 + lane];
    float vkl = Qsum[((size_t)b * NHEAD + h) * 64 + lane];
    float* sip = si_out + ((size_t)b * NHEAD + h) * S_LEN;
    int s0 = blockIdx.y * 128 + wv * 32;
    float aq = 0.f, ak = 0.f;
    for (int i = 0; i < 32; ++i) {
        int s = s0 + i;
        float qv = b2f(qp[(size_t)s * DMODEL]);
        float kv = b2f(kp[(size_t)s * DMODEL]);
        float dq = qv * vql, dk = kv * vkl;
        #pragma unroll
        for (int off = 32; off; off >>= 1) {
            dq += __shfl_xor(dq, off);
            dk += __shfl_xor(dk, off);
        }
        float si_ = 1.f / dq, so_ = 1.f / dk;
        if (lane == 0) sip[s] = si_;
        aq += qv * si_;
        ak += kv * so_;
    }
    atomicAdd(&qsi[((size_t)b * NHEAD + h) * 64 + lane], aq);
    atomicAdd(&kso[((size_t)b * NHEAD + h) * 64 + lane], ak);
}

// ---- per-s dots with a per-head 64-vector, batched over b (z) ----
__global__ void dots_k(const ushort* __restrict__ Q, const ushort* __restrict__ K,
                       const float* __restrict__ vq, const float* __restrict__ vk,
                       float* __restrict__ outq, float* __restrict__ outk, int invert) {
    int h = blockIdx.x;
    int b = blockIdx.z;
    const ushort* Qb = Q + (size_t)b * BROWS * DMODEL;
    const ushort* Kb = K + (size_t)b * BROWS * DMODEL;
    const float* vqb = vq + (size_t)b * NHEAD * 64;
    const float* vkb = vk + (size_t)b * NHEAD * 64;
    float* oq = outq + (size_t)b * NHEAD * S_LEN;
    float* ok = outk + (size_t)b * NHEAD * S_LEN;
    int lane = threadIdx.x & 63, wv = threadIdx.x >> 6;
    const ushort* qp = Qb + h * 64 + lane;
    const ushort* kp = Kb + h * 64 + lane;
    float vql = vqb[h * 64 + lane];
    float vkl = vkb[h * 64 + lane];
    int s0 = blockIdx.y * 128 + wv * 32;
    for (int i = 0; i < 32; ++i) {
        int s = s0 + i;
        float dq = b2f(qp[(size_t)s * DMODEL]) * vql;
        float dk = b2f(kp[(size_t)s * DMODEL]) * vkl;
        #pragma unroll
        for (int off = 32; off; off >>= 1) {
            dq += __shfl_xor(dq, off);
            dk += __shfl_xor(dk, off);
        }
        if (lane == 0) {
            oq[(size_t)h * S_LEN + s] = invert ? 1.f / dq : dq;
            ok[(size_t)h * S_LEN + s] = invert ? 1.f / dk : dk;
        }
    }
}

// ---- softmax over S per head, batched over b (y); safe in-place (w may == x) ----
__global__ void softmax_k(const float* x, float* w) {
    int h = blockIdx.x;
    int b = blockIdx.y;
    const float* xp = x + ((size_t)b * NHEAD + h) * S_LEN;
    float* wp = w + ((size_t)b * NHEAD + h) * S_LEN;
    float loc[16];
    float mx = -1e30f;
    #pragma unroll
    for (int i = 0; i < 16; ++i) { loc[i] = xp[threadIdx.x + i * 256]; mx = fmaxf(mx, loc[i]); }
    __shared__ float red[256];
    red[threadIdx.x] = mx; __syncthreads();
    for (int st = 128; st; st >>= 1) {
        if (threadIdx.x < st) red[threadIdx.x] = fmaxf(red[threadIdx.x], red[threadIdx.x + st]);
        __syncthreads();
    }
    mx = red[0]; __syncthreads();
    float sm = 0.f;
    #pragma unroll
    for (int i = 0; i < 16; ++i) { loc[i] = __expf(loc[i] - mx); sm += loc[i]; }
    red[threadIdx.x] = sm; __syncthreads();
    for (int st = 128; st; st >>= 1) {
        if (threadIdx.x < st) red[threadIdx.x] += red[threadIdx.x + st];
        __syncthreads();
    }
    float inv = 1.f / red[0];
    #pragma unroll
    for (int i = 0; i < 16; ++i)
        wp[threadIdx.x + i * 256] = loc[i] * inv;
}

// ---- kv[h,k,v] = sum_s (K[s,k]*w[h,s]) * V[s,v], one batch (split-S atomics) ----
// XCD remap: same-s blocks (all 16 h) co-locate on one XCD (K rows fetched once/XCD).
__global__ __launch_bounds__(256) void kv_k(const ushort* __restrict__ K,
                                            const ushort* __restrict__ V,
                                            const float* __restrict__ w,
                                            float* __restrict__ kv) {
    int bid = (int)(blockIdx.y * gridDim.x + blockIdx.x);   // gridDim = (16, 16)
    int lid = (bid & 7) * 32 + (bid >> 3);
    int h = lid & 15;
    int sy = lid >> 4;
    __shared__ __align__(16) float  KwS[64 * 64];
    __shared__ __align__(16) ushort Vt[64 * 64];
    int t = threadIdx.x;
    int kk = (t & 31) * 2;          // k pair
    int v0 = (t >> 5) * 8;          // v oct
    float acc[2][8];
    #pragma unroll
    for (int i = 0; i < 2; ++i)
        #pragma unroll
        for (int j = 0; j < 8; ++j) acc[i][j] = 0.f;
    int sl_s = t >> 2, q = t & 3;   // staging: row, quarter
    int sBase = sy * (S_LEN / KV_SPLIT);
    for (int t0 = 0; t0 < S_LEN / KV_SPLIT; t0 += 64) {
        __syncthreads();
        // V tile: 8KB linear, 2 DMA rounds
        #pragma unroll
        for (int r = 0; r < 2; ++r) {
            int o = t * 16 + r * 4096;
            int row = o >> 7;
            gld_lds16((char*)Vt + o,
                      V + (size_t)(sBase + t0 + row) * DMODEL + h * 64 + ((o & 127) >> 1));
        }
        // K tile: reg-staged f32 * w, swizzled
        {
            int s = sBase + t0 + sl_s;
            float ws = w[(size_t)h * S_LEN + s];
            const ushort* kp = K + (size_t)s * DMODEL + h * 64 + q * 16;
            uint4 ka = *(const uint4*)kp;
            uint4 kb = *(const uint4*)(kp + 8);
            int swz = (sl_s & 7) << 4;
            char* base = (char*)KwS + sl_s * 256;
            f32x4 c0 = { blo(ka.x) * ws, bhi(ka.x) * ws, blo(ka.y) * ws, bhi(ka.y) * ws };
            f32x4 c1 = { blo(ka.z) * ws, bhi(ka.z) * ws, blo(ka.w) * ws, bhi(ka.w) * ws };
            f32x4 c2 = { blo(kb.x) * ws, bhi(kb.x) * ws, blo(kb.y) * ws, bhi(kb.y) * ws };
            f32x4 c3 = { blo(kb.z) * ws, bhi(kb.z) * ws, blo(kb.w) * ws, bhi(kb.w) * ws };
            *(f32x4*)(base + ((q * 64 +  0) ^ swz)) = c0;
            *(f32x4*)(base + ((q * 64 + 16) ^ swz)) = c1;
            *(f32x4*)(base + ((q * 64 + 32) ^ swz)) = c2;
            *(f32x4*)(base + ((q * 64 + 48) ^ swz)) = c3;
        }
        __syncthreads();
        #pragma unroll 2
        for (int sl = 0; sl < 64; ++sl) {
            int swz = (sl & 7) << 4;
            float2 kf = *(const float2*)((const char*)KwS + sl * 256 + ((kk * 4) ^ swz));
            uint4 vv = *(const uint4*)((const char*)Vt + sl * 128 + v0 * 2);
            float vf0 = blo(vv.x), vf1 = bhi(vv.x), vf2 = blo(vv.y), vf3 = bhi(vv.y);
            float vf4 = blo(vv.z), vf5 = bhi(vv.z), vf6 = blo(vv.w), vf7 = bhi(vv.w);
            acc[0][0] += kf.x * vf0; acc[0][1] += kf.x * vf1;
            acc[0][2] += kf.x * vf2; acc[0][3] += kf.x * vf3;
            acc[0][4] += kf.x * vf4; acc[0][5] += kf.x * vf5;
            acc[0][6] += kf.x * vf6; acc[0][7] += kf.x * vf7;
            acc[1][0] += kf.y * vf0; acc[1][1] += kf.y * vf1;
            acc[1][2] += kf.y * vf2; acc[1][3] += kf.y * vf3;
            acc[1][4] += kf.y * vf4; acc[1][5] += kf.y * vf5;
            acc[1][6] += kf.y * vf6; acc[1][7] += kf.y * vf7;
        }
    }
    float* kvp = kv + (size_t)h * 4096;
    #pragma unroll
    for (int i = 0; i < 2; ++i)
        #pragma unroll
        for (int j = 0; j < 8; ++j)
            atomicAdd(&kvp[(kk + i) * 64 + v0 + j], acc[i][j]);
}

// ---- ctx[s,h*64+v] = sig(csink[h,s])*si[h,s]*sum_k Q[s,h*64+k]*kv[h,k,v] ----
__global__ __launch_bounds__(256) void ctx_k(const ushort* __restrict__ Q,
                                             const float* __restrict__ kv,
                                             const float* __restrict__ si,
                                             const float* __restrict__ csink,
                                             ushort* __restrict__ ctx) {
    int bid = (int)(blockIdx.y * gridDim.x + blockIdx.x);   // gridDim = (16, 16)
    int lid = (bid & 7) * 32 + (bid >> 3);
    int h = lid & 15;
    int sBlock = (lid >> 4) * 256;
    __shared__ __align__(16) float  kvf[64 * 64];   // [k][v] linear
    __shared__ __align__(16) ushort Qt[64 * 64];    // [s][k] source-preswizzled
    int t = threadIdx.x;
    {
        const float* kp = kv + (size_t)h * 4096;
        #pragma unroll
        for (int i = 0; i < 4; ++i) {
            int idx = t * 4 + i * 1024;
            *(f32x4*)&kvf[idx] = *(const f32x4*)&kp[idx];
        }
    }
    int spair = t >> 3;            // 0..31
    int v0 = (t & 7) * 8;
    for (int tile = 0; tile < 4; ++tile) {
        __syncthreads();           // prev-tile reads done (also covers kvf stage)
        int sT = sBlock + tile * 64;
        #pragma unroll
        for (int r = 0; r < 2; ++r) {
            int o = t * 16 + r * 4096;
            int row = o >> 7;
            int cb = (o & 127) ^ ((row & 7) << 4);
            gld_lds16((char*)Qt + o, Q + (size_t)(sT + row) * DMODEL + h * 64 + (cb >> 1));
        }
        __syncthreads();
        int s0 = spair * 2, s1 = s0 + 1;
        int swz0 = (s0 & 7) << 4, swz1 = (s1 & 7) << 4;
        float acc0[8], acc1[8];
        #pragma unroll
        for (int j = 0; j < 8; ++j) { acc0[j] = 0.f; acc1[j] = 0.f; }
        #pragma unroll 4
        for (int k = 0; k < 64; k += 4) {
            union { ushort4 v; ushort u[4]; } qa, qb;
            qa.v = *(const ushort4*)((const char*)Qt + s0 * 128 + ((k * 2) ^ swz0));
            qb.v = *(const ushort4*)((const char*)Qt + s1 * 128 + ((k * 2) ^ swz1));
            const char* rbase = (const char*)kvf + k * 256 + v0 * 4;
            #pragma unroll
            for (int kk2 = 0; kk2 < 4; ++kk2) {
                f32x4 r0 = *(const f32x4*)(rbase + kk2 * 256);
                f32x4 r1 = *(const f32x4*)(rbase + kk2 * 256 + 16);
                float qaf = b2f(qa.u[kk2]);
                float qbf = b2f(qb.u[kk2]);
                #pragma unroll
                for (int j = 0; j < 4; ++j) {
                    acc0[j]     += qaf * r0[j];
                    acc0[4 + j] += qaf * r1[j];
                    acc1[j]     += qbf * r0[j];
                    acc1[4 + j] += qbf * r1[j];
                }
            }
        }
        int gs0 = sT + s0, gs1 = sT + s1;
        float sc0 = si[(size_t)h * S_LEN + gs0] * sigmoidf_(csink[(size_t)h * S_LEN + gs0]);
        float sc1 = si[(size_t)h * S_LEN + gs1] * sigmoidf_(csink[(size_t)h * S_LEN + gs1]);
        union { ushort u[8]; uint4 v; } o0, o1;
        #pragma unroll
        for (int j = 0; j < 8; ++j) {
            o0.u[j] = f2b(acc0[j] * sc0);
            o1.u[j] = f2b(acc1[j] * sc1);
        }
        *(uint4*)(ctx + (size_t)gs0 * DMODEL + h * 64 + v0) = o0.v;
        *(uint4*)(ctx + (size_t)gs1 * DMODEL + h * 64 + v0) = o1.v;
    }
}

// ---- LayerNorm(y_bf16 + residual_f32) * gamma + beta -> fp32 out (per-row) ----
__global__ void ln_k(const ushort* __restrict__ y, const float* __restrict__ res,
                     const float* __restrict__ gamma, const float* __restrict__ beta,
                     float* __restrict__ out) {
    size_t row = blockIdx.x;
    const ushort* yp = y + row * DMODEL;
    const float* rp = res + row * DMODEL;
    float x[4];
    float s = 0.f, s2 = 0.f;
    #pragma unroll
    for (int i = 0; i < 4; ++i) {
        int d = threadIdx.x + i * 256;
        x[i] = b2f(yp[d]) + rp[d];
        s += x[i]; s2 += x[i] * x[i];
    }
    __shared__ float r1[256], r2[256];
    r1[threadIdx.x] = s; r2[threadIdx.x] = s2;
    __syncthreads();
    for (int st = 128; st; st >>= 1) {
        if (threadIdx.x < st) { r1[threadIdx.x] += r1[threadIdx.x + st]; r2[threadIdx.x] += r2[threadIdx.x + st]; }
        __syncthreads();
    }
    float mean = r1[0] * (1.f / DMODEL);
    float var = r2[0] * (1.f / DMODEL) - mean * mean;
    float rstd = rsqrtf(var + 1e-5f);
    #pragma unroll
    for (int i = 0; i < 4; ++i) {
        int d = threadIdx.x + i * 256;
        out[row * DMODEL + d] = (x[i] - mean) * rstd * gamma[d] + beta[d];
    }
}

extern "C" void kernel_launch(void* const* d_in, const int* in_sizes, int n_in,
                              void* d_out, int out_size, void* d_ws, size_t ws_size,
                              hipStream_t stream) {
    const float* inQ  = (const float*)d_in[0];
    const float* inK  = (const float*)d_in[1];
    const float* inV  = (const float*)d_in[2];
    const float* WQ   = (const float*)d_in[3];
    const float* WK   = (const float*)d_in[4];
    const float* WV   = (const float*)d_in[5];
    const float* WF   = (const float*)d_in[6];
    const float* gamma= (const float*)d_in[7];
    const float* beta = (const float*)d_in[8];
    float* outf = (float*)d_out;

    // d_out scratch: bf16 Q at [0,32MB), bf16 K/ctx at [32,64MB)
    ushort* Qb  = (ushort*)d_out;
    ushort* KCb = (ushort*)d_out + (size_t)NROWS * DMODEL;

    // d_ws layout (peak 13.31MB < proven 13.6MB):
    const size_t MB = 1024ull * 1024ull;
    char* w = (char*)d_ws;
    ushort* Vb  = (ushort*)w;                 // [4096][1024] bf16, 8MB; later O_b slot
    ushort* Wt  = (ushort*)(w + 8 * MB);      // 2MB weight^T slot (WQ->WK->WV->WF)
    float* si    = (float*)(w + 10 * MB);     // [4][16][4096] f32, 1MB
    float* soCsk = si + 4 * NHEAD * S_LEN;    // 1MB: csk (dots2)
    float* css   = soCsk + 4 * NHEAD * S_LEN; // 1MB: css -> smw (softmax in-place)
    float* Qsum  = css + 4 * NHEAD * S_LEN;   // 4 sum buffers x [4][16][64] = 64KB
    float* Ksum  = Qsum + 4 * NHEAD * 64;
    float* QsI   = Ksum + 4 * NHEAD * 64;
    float* KsO   = QsI  + 4 * NHEAD * 64;
    float* kvb   = KsO  + 4 * NHEAD * 64;     // [16][64][64] f32, 256KB (per-batch)
    size_t sumZeroBytes = 4 * 4 * NHEAD * 64 * sizeof(float);   // 64KB
    size_t kvZeroBytes  = (size_t)NHEAD * 4096 * sizeof(float); // 256KB

    dim3 tb(32, 8);
    dim3 tg(32, 32);
    dim3 ggFull(DMODEL / 128, NROWS / 128);   // (8, 128)
    dim3 ggBat(DMODEL / 128, BROWS / 128);    // (8, 32)

    // zero Qsum/Ksum/QsI/KsO before gemm epilogue atomics
    hipMemsetAsync(Qsum, 0, sumZeroBytes, stream);

    // Phase 1: Q and K projections (full batch) into d_out; epilogue colsums
    transpose_k<<<tg, tb, 0, stream>>>(WQ, Wt);
    gemm128<1><<<ggFull, 256, 0, stream>>>(inQ, 0, Wt, Qb, 1, Qsum);
    transpose_k<<<tg, tb, 0, stream>>>(WK, Wt);
    gemm128<1><<<ggFull, 256, 0, stream>>>(inK, 0, Wt, KCb, 1, Ksum);
    transpose_k<<<tg, tb, 0, stream>>>(WV, Wt);   // WVt stays through P2

    // Stats: fused dots1(+colsum2), dots2, softmax — all 4 batches per launch
    dots1_k<<<dim3(NHEAD, 32, 4), 256, 0, stream>>>(Qb, KCb, Qsum, Ksum, si, QsI, KsO);
    dots_k<<<dim3(NHEAD, 32, 4), 256, 0, stream>>>(Qb, KCb, KsO, QsI, soCsk, css, 0);
    softmax_k<<<dim3(NHEAD, 4), 256, 0, stream>>>(css, css);

    // Phase 2: per-batch V projection + kv + ctx (ctx_b overwrites dead K_b slice)
    for (int b = 0; b < 4; ++b) {
        size_t rowOff = (size_t)b * BROWS * DMODEL;
        size_t statOff = (size_t)b * NHEAD * S_LEN;
        const ushort* Qs = Qb + rowOff;
        ushort* Ks = KCb + rowOff;
        gemm128<1><<<ggBat, 256, 0, stream>>>(inV, rowOff, Wt, Vb, 0, nullptr);
        hipMemsetAsync(kvb, 0, kvZeroBytes, stream);
        kv_k<<<dim3(NHEAD, KV_SPLIT), 256, 0, stream>>>(Ks, Vb, css + statOff, kvb);
        ctx_k<<<dim3(NHEAD, 16), 256, 0, stream>>>(Qs, kvb, si + statOff, soCsk + statOff, Ks);
    }

    // Phase 3: output projection + LayerNorm (fp32 out)
    transpose_k<<<tg, tb, 0, stream>>>(WF, Wt);   // WVt dead now
    for (int b = 0; b < 4; ++b) {
        size_t rowOff = (size_t)b * BROWS * DMODEL;
        gemm128<0><<<ggBat, 256, 0, stream>>>(KCb + rowOff, 0, Wt, Vb, 0, nullptr);
        ln_k<<<BROWS, 256, 0, stream>>>(Vb, inQ + rowOff, gamma, beta, outf + rowOff);
    }
}

// Round 6
// 1020.530 us; speedup vs baseline: 1.0030x; 1.0030x over previous
//
#include <hip/hip_runtime.h>
#include <hip/hip_bf16.h>

// FlowAttention: B=4 S=4096 D=1024 H=16 dk=dv=64. Inputs/outputs fp32.
// Round-11: AF32 gemm pipelined (T14 + minimum-2-phase).
//  R5 post-mortem: reg-staged conversion put A-load latency INSIDE staging
//  (barrier->load->wait->pack->write->barrier): 121us vs R3's 93us. Fix:
//   - B tile double-buffered (2x16KB); B-DMA(k+1) issued BEFORE compute(k),
//     drained by the post-compute barrier (latency hides under 32 MFMAs).
//   - A prefetched to REGISTERS one tile ahead (8x dwordx4 issued before
//     compute); pack (cvt_pk via native __bf16 casts) + 4 swizzled ds_write
//     land in the short window between the two barriers.
//   - LDS 48KB -> 3 blocks/CU; only ~16 cvt + 4 ds_write exposed per iter.
//  bf16 path (P3) and all other kernels unchanged from R5 (proven).
// Phase order (race-audited, unchanged):
//   memset sums; P1: Q->dout[0,32), K->dout[32,64) (epilogue colsums); WV^T stays
//   stats: dots1_k, dots2(dots_k), softmax(in-place)
//   P2 per b: V_b->ws (AF32 gemm); memset kvb; kv_k; ctx_b overwrites dead K_b
//   WF^T; P3 per b: O_b = ctx_b@Wfc -> ws slot; LN -> dout fp32 rows of b
#define S_LEN 4096
#define DMODEL 1024
#define NHEAD 16
#define NROWS 16384      // B*S
#define BROWS 4096       // rows per batch
#define KV_SPLIT 16

typedef __bf16 bf16x8 __attribute__((ext_vector_type(8)));
typedef float  f32x4  __attribute__((ext_vector_type(4)));

__device__ __forceinline__ float b2f(ushort u) {
    union { uint i; float f; } c; c.i = ((uint)u) << 16; return c.f;
}
__device__ __forceinline__ float blo(uint u) {
    union { uint i; float f; } c; c.i = u << 16; return c.f;
}
__device__ __forceinline__ float bhi(uint u) {
    union { uint i; float f; } c; c.i = u & 0xFFFF0000u; return c.f;
}
__device__ __forceinline__ ushort f2b(float f) {
    union { uint i; float f; } c; c.f = f;
    uint r = c.i + 0x7FFF + ((c.i >> 16) & 1);   // round-to-nearest-even
    return (ushort)(r >> 16);
}
__device__ __forceinline__ float sigmoidf_(float x) {
    return 1.f / (1.f + __expf(-x));
}

// async 16B global->LDS DMA. Dest must be thread-linear (base + tid*16).
__device__ __forceinline__ void gld_lds16(void* lds, const void* g) {
    __builtin_amdgcn_global_load_lds(
        (const __attribute__((address_space(1))) uint*)g,
        (__attribute__((address_space(3))) uint*)lds, 16, 0, 0);
}

// pack 32 fp32 (8x float4) -> 4x bf16x8 ds_write_b128 at swizzled offsets.
// native __bf16 casts -> v_cvt_pk_bf16_f32 (RNE, same as f2b).
__device__ __forceinline__ void packA8(const float4* qn, char* smA, const int* awb) {
    #pragma unroll
    for (int j = 0; j < 4; ++j) {
        bf16x8 pk;
        pk[0] = (__bf16)qn[2 * j].x;     pk[1] = (__bf16)qn[2 * j].y;
        pk[2] = (__bf16)qn[2 * j].z;     pk[3] = (__bf16)qn[2 * j].w;
        pk[4] = (__bf16)qn[2 * j + 1].x; pk[5] = (__bf16)qn[2 * j + 1].y;
        pk[6] = (__bf16)qn[2 * j + 1].z; pk[7] = (__bf16)qn[2 * j + 1].w;
        *(bf16x8*)(smA + awb[j]) = pk;
    }
}

// ---------------- transpose 1024x1024: out[n][k] = bf16(in[k][n]), in fp32 ------
__global__ void transpose_k(const float* __restrict__ in, ushort* __restrict__ out) {
    __shared__ ushort tile[32][33];
    int x = blockIdx.x * 32 + threadIdx.x;
    int y0 = blockIdx.y * 32;
    for (int i = threadIdx.y; i < 32; i += 8)
        tile[i][threadIdx.x] = f2b(in[(size_t)(y0 + i) * DMODEL + x]);
    __syncthreads();
    int xo = blockIdx.y * 32 + threadIdx.x;
    int yo0 = blockIdx.x * 32;
    for (int i = threadIdx.y; i < 32; i += 8)
        out[(size_t)(yo0 + i) * DMODEL + xo] = tile[threadIdx.x][i];
}

// ---------------- MFMA GEMM: C[M,1024] = act(A[M,1024] @ Bt^T) ------------------
// 128x128 tile, 4 waves 2x2, each wave 64x64 via 4x4 mfma 16x16x32 bf16. BK=64.
// AF32 (48KB LDS): bufB[2] bf16 [128][64] @0/@16K (dbuf), smA bf16 [128][64] @32K.
//   loop it: { issue B-DMA(it+1)->bufB^1; issue A-loads(it+1)->regs;
//              compute(it) from smA+bufB[cur]; barrier (drains both);
//              pack+ds_write A(it+1)->smA; barrier; }
// bf16 (32KB LDS): R5's 2-barrier gld_lds structure, unchanged.
// Swizzle byte_in_row ^= (row&7)<<4 on all tiles (inverse on global src for DMA,
// write-side for reg-staged A); read-side always. XCD swizzle:
// lid=(bid&7)*(nwg/8)+bid/8 (nwg divisible by 8; gridDim.x==8).
// csum != nullptr: epilogue per-column sums of stored output into csum[b][h][64].
template<int AF32>
__global__ __launch_bounds__(256) void gemm128(const void* __restrict__ A, size_t aoff,
                                               const ushort* __restrict__ Bt,
                                               ushort* __restrict__ C, int act,
                                               float* __restrict__ csum) {
    constexpr int SMEM_BYTES = AF32 ? 49152 : 32768;
    __shared__ __align__(16) char smem[SMEM_BYTES];

    int nwg = (int)(gridDim.x * gridDim.y);
    int bid = (int)(blockIdx.y * gridDim.x + blockIdx.x);
    int lid = (bid & 7) * (nwg >> 3) + (bid >> 3);
    int n0 = (lid & 7) * 128;                     // gridDim.x == 8
    int m0 = (lid >> 3) * 128;

    int t = threadIdx.x;
    int lane = t & 63, wave = t >> 6;
    int wm = (wave >> 1) * 64, wn = (wave & 1) * 64;
    int fr = lane & 15;            // frag row (A) / col (B)
    int kq = (lane >> 4) * 8;      // k offset within 32-step

    const float*  Af = (const float*)A + aoff;
    const ushort* Ab = (const ushort*)A + aoff;

    // staging descriptors (k0-invariant) for gld_lds rounds
    int ldsOff[4], rowOf[4], bcB[4];
    #pragma unroll
    for (int r = 0; r < 4; ++r) {
        int o = t * 16 + r * 4096;
        int row = o >> 7;
        ldsOff[r] = o;
        rowOf[r] = row;
        bcB[r] = (o & 127) ^ ((row & 7) << 4);
    }

    f32x4 acc[4][4];
    #pragma unroll
    for (int i = 0; i < 4; ++i)
        #pragma unroll
        for (int j = 0; j < 4; ++j) acc[i][j] = (f32x4){0.f, 0.f, 0.f, 0.f};

    if (AF32) {
        char* smA = smem + 32768;
        // A reg-stage geometry: thread t covers row=t>>1, k in [akh, akh+32)
        int arow = t >> 1;
        int akh = (t & 1) * 32;
        const float* aptr = Af + (size_t)(m0 + arow) * DMODEL + akh;
        int awb[4];                                // swizzled ds_write byte offsets
        #pragma unroll
        for (int j = 0; j < 4; ++j)
            awb[j] = ((arow << 7) + akh * 2 + j * 16) ^ ((arow & 7) << 4);

        float4 qn[8];
        // prologue: tile 0 (A loads -> pack -> smA; B DMA -> bufB0)
        #pragma unroll
        for (int j = 0; j < 8; ++j) qn[j] = *(const float4*)(aptr + j * 4);
        #pragma unroll
        for (int r = 0; r < 4; ++r)
            gld_lds16(smem + ldsOff[r],
                      Bt + (size_t)(n0 + rowOf[r]) * DMODEL + (bcB[r] >> 1));
        packA8(qn, smA, awb);        // compiler waits qn loads here
        __syncthreads();             // drains B-DMA + A ds_writes

        for (int it = 0; it < 16; ++it) {
            int cur = it & 1;
            if (it < 15) {
                int kn = (it + 1) * 64;
                // issue next B tile DMA into the other buffer (overlaps compute)
                #pragma unroll
                for (int r = 0; r < 4; ++r)
                    gld_lds16(smem + (cur ^ 1) * 16384 + ldsOff[r],
                              Bt + (size_t)(n0 + rowOf[r]) * DMODEL + kn + (bcB[r] >> 1));
                // issue next A loads into registers (overlaps compute)
                #pragma unroll
                for (int j = 0; j < 8; ++j) qn[j] = *(const float4*)(aptr + kn + j * 4);
            }
            // compute tile it from smA + bufB[cur]
            const char* bB = smem + cur * 16384;
            #pragma unroll
            for (int h = 0; h < 2; ++h) {
                bf16x8 av[4], bv[4];
                #pragma unroll
                for (int i = 0; i < 4; ++i) {
                    int row = wm + i * 16 + fr;
                    int k = h * 32 + kq;
                    int o = ((row << 7) + (k << 1)) ^ ((row & 7) << 4);
                    av[i] = *(const bf16x8*)(smA + o);
                }
                #pragma unroll
                for (int j = 0; j < 4; ++j) {
                    int nrow = wn + j * 16 + fr;
                    int k = h * 32 + kq;
                    int o = ((nrow << 7) + (k << 1)) ^ ((nrow & 7) << 4);
                    bv[j] = *(const bf16x8*)(bB + o);
                }
                #pragma unroll
                for (int i = 0; i < 4; ++i)
                    #pragma unroll
                    for (int j = 0; j < 4; ++j)
                        acc[i][j] = __builtin_amdgcn_mfma_f32_16x16x32_bf16(av[i], bv[j], acc[i][j], 0, 0, 0);
            }
            if (it < 15) {
                __syncthreads();          // smA reads done; drains B-DMA + qn loads
                packA8(qn, smA, awb);     // short exposed window: 16 cvt + 4 ds_write
                __syncthreads();          // A(it+1) visible before next compute
            }
        }
    } else {
        char* smA = smem + 16384;
        for (int k0 = 0; k0 < DMODEL; k0 += 64) {
            __syncthreads();   // prev iteration's LDS reads done before overwrite
            #pragma unroll
            for (int r = 0; r < 4; ++r)
                gld_lds16(smem + ldsOff[r],
                          Bt + (size_t)(n0 + rowOf[r]) * DMODEL + k0 + (bcB[r] >> 1));
            #pragma unroll
            for (int r = 0; r < 4; ++r)
                gld_lds16(smA + ldsOff[r],
                          Ab + (size_t)(m0 + rowOf[r]) * DMODEL + k0 + (bcB[r] >> 1));
            __syncthreads();   // drains DMA

            #pragma unroll
            for (int h = 0; h < 2; ++h) {
                bf16x8 av[4], bv[4];
                #pragma unroll
                for (int i = 0; i < 4; ++i) {
                    int row = wm + i * 16 + fr;
                    int k = h * 32 + kq;
                    int o = ((row << 7) + (k << 1)) ^ ((row & 7) << 4);
                    av[i] = *(const bf16x8*)(smA + o);
                }
                #pragma unroll
                for (int j = 0; j < 4; ++j) {
                    int nrow = wn + j * 16 + fr;
                    int k = h * 32 + kq;
                    int o = ((nrow << 7) + (k << 1)) ^ ((nrow & 7) << 4);
                    bv[j] = *(const bf16x8*)(smem + o);
                }
                #pragma unroll
                for (int i = 0; i < 4; ++i)
                    #pragma unroll
                    for (int j = 0; j < 4; ++j)
                        acc[i][j] = __builtin_amdgcn_mfma_f32_16x16x32_bf16(av[i], bv[j], acc[i][j], 0, 0, 0);
            }
        }
    }

    int rbase = (lane >> 4) * 4;
    int cix = lane & 15;
    float colacc[4] = {0.f, 0.f, 0.f, 0.f};
    #pragma unroll
    for (int i = 0; i < 4; ++i)
        #pragma unroll
        for (int j = 0; j < 4; ++j) {
            int col = n0 + wn + j * 16 + cix;
            #pragma unroll
            for (int r = 0; r < 4; ++r) {
                int row = m0 + wm + i * 16 + rbase + r;
                float v = acc[i][j][r];
                if (act) v = sigmoidf_(v);
                ushort ub = f2b(v);
                C[(size_t)row * DMODEL + col] = ub;
                if (csum) colacc[j] += b2f(ub);
            }
        }
    if (csum) {
        __syncthreads();                // all LDS frag reads done; reuse smem
        float* cred = (float*)smem;     // [2][128]
        cred[t] = 0.f;
        __syncthreads();
        #pragma unroll
        for (int j = 0; j < 4; ++j) {
            float s = colacc[j];
            s += __shfl_xor(s, 16);
            s += __shfl_xor(s, 32);     // sum over wave's 64 rows
            if (lane < 16) cred[(wm >> 6) * 128 + wn + j * 16 + lane] = s;
        }
        __syncthreads();
        if (t < 128) {
            float tot = cred[t] + cred[128 + t];
            int col = n0 + t;
            int b = m0 >> 12;           // 4096 rows per batch
            atomicAdd(&csum[((size_t)b * NHEAD + (col >> 6)) * 64 + (col & 63)], tot);
        }
    }
}

// ---- fused dots1 + weighted colsum2, batched over b (z) ----
// dq = Q[s]·Ksum -> si = 1/dq (stored); dk = K[s]·Qsum -> so = 1/dk (not stored)
// QsI[d] += sum_s Q[s,d]*si[s] ; KsO[d] += sum_s K[s,d]*so[s]  (atomic per wave-lane)
__global__ void dots1_k(const ushort* __restrict__ Q, const ushort* __restrict__ K,
                        const float* __restrict__ Qsum, const float* __restrict__ Ksum,
                        float* __restrict__ si_out, float* __restrict__ qsi,
                        float* __restrict__ kso) {
    int h = blockIdx.x, b = blockIdx.z;
    int lane = threadIdx.x & 63, wv = threadIdx.x >> 6;
    const ushort* qp = Q + (size_t)b * BROWS * DMODEL + h * 64 + lane;
    const ushort* kp = K + (size_t)b * BROWS * DMODEL + h * 64 + lane;
    float vql = Ksum[((size_t)b * NHEAD + h) * 64 + lane];
    float vkl = Qsum[((size_t)b * NHEAD + h) * 64 + lane];
    float* sip = si_out + ((size_t)b * NHEAD + h) * S_LEN;
    int s0 = blockIdx.y * 128 + wv * 32;
    float aq = 0.f, ak = 0.f;
    for (int i = 0; i < 32; ++i) {
        int s = s0 + i;
        float qv = b2f(qp[(size_t)s * DMODEL]);
        float kv = b2f(kp[(size_t)s * DMODEL]);
        float dq = qv * vql, dk = kv * vkl;
        #pragma unroll
        for (int off = 32; off; off >>= 1) {
            dq += __shfl_xor(dq, off);
            dk += __shfl_xor(dk, off);
        }
        float si_ = 1.f / dq, so_ = 1.f / dk;
        if (lane == 0) sip[s] = si_;
        aq += qv * si_;
        ak += kv * so_;
    }
    atomicAdd(&qsi[((size_t)b * NHEAD + h) * 64 + lane], aq);
    atomicAdd(&kso[((size_t)b * NHEAD + h) * 64 + lane], ak);
}

// ---- per-s dots with a per-head 64-vector, batched over b (z) ----
__global__ void dots_k(const ushort* __restrict__ Q, const ushort* __restrict__ K,
                       const float* __restrict__ vq, const float* __restrict__ vk,
                       float* __restrict__ outq, float* __restrict__ outk, int invert) {
    int h = blockIdx.x;
    int b = blockIdx.z;
    const ushort* Qb = Q + (size_t)b * BROWS * DMODEL;
    const ushort* Kb = K + (size_t)b * BROWS * DMODEL;
    const float* vqb = vq + (size_t)b * NHEAD * 64;
    const float* vkb = vk + (size_t)b * NHEAD * 64;
    float* oq = outq + (size_t)b * NHEAD * S_LEN;
    float* ok = outk + (size_t)b * NHEAD * S_LEN;
    int lane = threadIdx.x & 63, wv = threadIdx.x >> 6;
    const ushort* qp = Qb + h * 64 + lane;
    const ushort* kp = Kb + h * 64 + lane;
    float vql = vqb[h * 64 + lane];
    float vkl = vkb[h * 64 + lane];
    int s0 = blockIdx.y * 128 + wv * 32;
    for (int i = 0; i < 32; ++i) {
        int s = s0 + i;
        float dq = b2f(qp[(size_t)s * DMODEL]) * vql;
        float dk = b2f(kp[(size_t)s * DMODEL]) * vkl;
        #pragma unroll
        for (int off = 32; off; off >>= 1) {
            dq += __shfl_xor(dq, off);
            dk += __shfl_xor(dk, off);
        }
        if (lane == 0) {
            oq[(size_t)h * S_LEN + s] = invert ? 1.f / dq : dq;
            ok[(size_t)h * S_LEN + s] = invert ? 1.f / dk : dk;
        }
    }
}

// ---- softmax over S per head, batched over b (y); safe in-place (w may == x) ----
__global__ void softmax_k(const float* x, float* w) {
    int h = blockIdx.x;
    int b = blockIdx.y;
    const float* xp = x + ((size_t)b * NHEAD + h) * S_LEN;
    float* wp = w + ((size_t)b * NHEAD + h) * S_LEN;
    float loc[16];
    float mx = -1e30f;
    #pragma unroll
    for (int i = 0; i < 16; ++i) { loc[i] = xp[threadIdx.x + i * 256]; mx = fmaxf(mx, loc[i]); }
    __shared__ float red[256];
    red[threadIdx.x] = mx; __syncthreads();
    for (int st = 128; st; st >>= 1) {
        if (threadIdx.x < st) red[threadIdx.x] = fmaxf(red[threadIdx.x], red[threadIdx.x + st]);
        __syncthreads();
    }
    mx = red[0]; __syncthreads();
    float sm = 0.f;
    #pragma unroll
    for (int i = 0; i < 16; ++i) { loc[i] = __expf(loc[i] - mx); sm += loc[i]; }
    red[threadIdx.x] = sm; __syncthreads();
    for (int st = 128; st; st >>= 1) {
        if (threadIdx.x < st) red[threadIdx.x] += red[threadIdx.x + st];
        __syncthreads();
    }
    float inv = 1.f / red[0];
    #pragma unroll
    for (int i = 0; i < 16; ++i)
        wp[threadIdx.x + i * 256] = loc[i] * inv;
}

// ---- kv[h,k,v] = sum_s (K[s,k]*w[h,s]) * V[s,v], one batch (split-S atomics) ----
// XCD remap: same-s blocks (all 16 h) co-locate on one XCD (K rows fetched once/XCD).
__global__ __launch_bounds__(256) void kv_k(const ushort* __restrict__ K,
                                            const ushort* __restrict__ V,
                                            const float* __restrict__ w,
                                            float* __restrict__ kv) {
    int bid = (int)(blockIdx.y * gridDim.x + blockIdx.x);   // gridDim = (16, 16)
    int lid = (bid & 7) * 32 + (bid >> 3);
    int h = lid & 15;
    int sy = lid >> 4;
    __shared__ __align__(16) float  KwS[64 * 64];
    __shared__ __align__(16) ushort Vt[64 * 64];
    int t = threadIdx.x;
    int kk = (t & 31) * 2;          // k pair
    int v0 = (t >> 5) * 8;          // v oct
    float acc[2][8];
    #pragma unroll
    for (int i = 0; i < 2; ++i)
        #pragma unroll
        for (int j = 0; j < 8; ++j) acc[i][j] = 0.f;
    int sl_s = t >> 2, q = t & 3;   // staging: row, quarter
    int sBase = sy * (S_LEN / KV_SPLIT);
    for (int t0 = 0; t0 < S_LEN / KV_SPLIT; t0 += 64) {
        __syncthreads();
        // V tile: 8KB linear, 2 DMA rounds
        #pragma unroll
        for (int r = 0; r < 2; ++r) {
            int o = t * 16 + r * 4096;
            int row = o >> 7;
            gld_lds16((char*)Vt + o,
                      V + (size_t)(sBase + t0 + row) * DMODEL + h * 64 + ((o & 127) >> 1));
        }
        // K tile: reg-staged f32 * w, swizzled
        {
            int s = sBase + t0 + sl_s;
            float ws = w[(size_t)h * S_LEN + s];
            const ushort* kp = K + (size_t)s * DMODEL + h * 64 + q * 16;
            uint4 ka = *(const uint4*)kp;
            uint4 kb = *(const uint4*)(kp + 8);
            int swz = (sl_s & 7) << 4;
            char* base = (char*)KwS + sl_s * 256;
            f32x4 c0 = { blo(ka.x) * ws, bhi(ka.x) * ws, blo(ka.y) * ws, bhi(ka.y) * ws };
            f32x4 c1 = { blo(ka.z) * ws, bhi(ka.z) * ws, blo(ka.w) * ws, bhi(ka.w) * ws };
            f32x4 c2 = { blo(kb.x) * ws, bhi(kb.x) * ws, blo(kb.y) * ws, bhi(kb.y) * ws };
            f32x4 c3 = { blo(kb.z) * ws, bhi(kb.z) * ws, blo(kb.w) * ws, bhi(kb.w) * ws };
            *(f32x4*)(base + ((q * 64 +  0) ^ swz)) = c0;
            *(f32x4*)(base + ((q * 64 + 16) ^ swz)) = c1;
            *(f32x4*)(base + ((q * 64 + 32) ^ swz)) = c2;
            *(f32x4*)(base + ((q * 64 + 48) ^ swz)) = c3;
        }
        __syncthreads();
        #pragma unroll 2
        for (int sl = 0; sl < 64; ++sl) {
            int swz = (sl & 7) << 4;
            float2 kf = *(const float2*)((const char*)KwS + sl * 256 + ((kk * 4) ^ swz));
            uint4 vv = *(const uint4*)((const char*)Vt + sl * 128 + v0 * 2);
            float vf0 = blo(vv.x), vf1 = bhi(vv.x), vf2 = blo(vv.y), vf3 = bhi(vv.y);
            float vf4 = blo(vv.z), vf5 = bhi(vv.z), vf6 = blo(vv.w), vf7 = bhi(vv.w);
            acc[0][0] += kf.x * vf0; acc[0][1] += kf.x * vf1;
            acc[0][2] += kf.x * vf2; acc[0][3] += kf.x * vf3;
            acc[0][4] += kf.x * vf4; acc[0][5] += kf.x * vf5;
            acc[0][6] += kf.x * vf6; acc[0][7] += kf.x * vf7;
            acc[1][0] += kf.y * vf0; acc[1][1] += kf.y * vf1;
            acc[1][2] += kf.y * vf2; acc[1][3] += kf.y * vf3;
            acc[1][4] += kf.y * vf4; acc[1][5] += kf.y * vf5;
            acc[1][6] += kf.y * vf6; acc[1][7] += kf.y * vf7;
        }
    }
    float* kvp = kv + (size_t)h * 4096;
    #pragma unroll
    for (int i = 0; i < 2; ++i)
        #pragma unroll
        for (int j = 0; j < 8; ++j)
            atomicAdd(&kvp[(kk + i) * 64 + v0 + j], acc[i][j]);
}

// ---- ctx[s,h*64+v] = sig(csink[h,s])*si[h,s]*sum_k Q[s,h*64+k]*kv[h,k,v] ----
__global__ __launch_bounds__(256) void ctx_k(const ushort* __restrict__ Q,
                                             const float* __restrict__ kv,
                                             const float* __restrict__ si,
                                             const float* __restrict__ csink,
                                             ushort* __restrict__ ctx) {
    int bid = (int)(blockIdx.y * gridDim.x + blockIdx.x);   // gridDim = (16, 16)
    int lid = (bid & 7) * 32 + (bid >> 3);
    int h = lid & 15;
    int sBlock = (lid >> 4) * 256;
    __shared__ __align__(16) float  kvf[64 * 64];   // [k][v] linear
    __shared__ __align__(16) ushort Qt[64 * 64];    // [s][k] source-preswizzled
    int t = threadIdx.x;
    {
        const float* kp = kv + (size_t)h * 4096;
        #pragma unroll
        for (int i = 0; i < 4; ++i) {
            int idx = t * 4 + i * 1024;
            *(f32x4*)&kvf[idx] = *(const f32x4*)&kp[idx];
        }
    }
    int spair = t >> 3;            // 0..31
    int v0 = (t & 7) * 8;
    for (int tile = 0; tile < 4; ++tile) {
        __syncthreads();           // prev-tile reads done (also covers kvf stage)
        int sT = sBlock + tile * 64;
        #pragma unroll
        for (int r = 0; r < 2; ++r) {
            int o = t * 16 + r * 4096;
            int row = o >> 7;
            int cb = (o & 127) ^ ((row & 7) << 4);
            gld_lds16((char*)Qt + o, Q + (size_t)(sT + row) * DMODEL + h * 64 + (cb >> 1));
        }
        __syncthreads();
        int s0 = spair * 2, s1 = s0 + 1;
        int swz0 = (s0 & 7) << 4, swz1 = (s1 & 7) << 4;
        float acc0[8], acc1[8];
        #pragma unroll
        for (int j = 0; j < 8; ++j) { acc0[j] = 0.f; acc1[j] = 0.f; }
        #pragma unroll 4
        for (int k = 0; k < 64; k += 4) {
            union { ushort4 v; ushort u[4]; } qa, qb;
            qa.v = *(const ushort4*)((const char*)Qt + s0 * 128 + ((k * 2) ^ swz0));
            qb.v = *(const ushort4*)((const char*)Qt + s1 * 128 + ((k * 2) ^ swz1));
            const char* rbase = (const char*)kvf + k * 256 + v0 * 4;
            #pragma unroll
            for (int kk2 = 0; kk2 < 4; ++kk2) {
                f32x4 r0 = *(const f32x4*)(rbase + kk2 * 256);
                f32x4 r1 = *(const f32x4*)(rbase + kk2 * 256 + 16);
                float qaf = b2f(qa.u[kk2]);
                float qbf = b2f(qb.u[kk2]);
                #pragma unroll
                for (int j = 0; j < 4; ++j) {
                    acc0[j]     += qaf * r0[j];
                    acc0[4 + j] += qaf * r1[j];
                    acc1[j]     += qbf * r0[j];
                    acc1[4 + j] += qbf * r1[j];
                }
            }
        }
        int gs0 = sT + s0, gs1 = sT + s1;
        float sc0 = si[(size_t)h * S_LEN + gs0] * sigmoidf_(csink[(size_t)h * S_LEN + gs0]);
        float sc1 = si[(size_t)h * S_LEN + gs1] * sigmoidf_(csink[(size_t)h * S_LEN + gs1]);
        union { ushort u[8]; uint4 v; } o0, o1;
        #pragma unroll
        for (int j = 0; j < 8; ++j) {
            o0.u[j] = f2b(acc0[j] * sc0);
            o1.u[j] = f2b(acc1[j] * sc1);
        }
        *(uint4*)(ctx + (size_t)gs0 * DMODEL + h * 64 + v0) = o0.v;
        *(uint4*)(ctx + (size_t)gs1 * DMODEL + h * 64 + v0) = o1.v;
    }
}

// ---- LayerNorm(y_bf16 + residual_f32) * gamma + beta -> fp32 out (per-row) ----
__global__ void ln_k(const ushort* __restrict__ y, const float* __restrict__ res,
                     const float* __restrict__ gamma, const float* __restrict__ beta,
                     float* __restrict__ out) {
    size_t row = blockIdx.x;
    const ushort* yp = y + row * DMODEL;
    const float* rp = res + row * DMODEL;
    float x[4];
    float s = 0.f, s2 = 0.f;
    #pragma unroll
    for (int i = 0; i < 4; ++i) {
        int d = threadIdx.x + i * 256;
        x[i] = b2f(yp[d]) + rp[d];
        s += x[i]; s2 += x[i] * x[i];
    }
    __shared__ float r1[256], r2[256];
    r1[threadIdx.x] = s; r2[threadIdx.x] = s2;
    __syncthreads();
    for (int st = 128; st; st >>= 1) {
        if (threadIdx.x < st) { r1[threadIdx.x] += r1[threadIdx.x + st]; r2[threadIdx.x] += r2[threadIdx.x + st]; }
        __syncthreads();
    }
    float mean = r1[0] * (1.f / DMODEL);
    float var = r2[0] * (1.f / DMODEL) - mean * mean;
    float rstd = rsqrtf(var + 1e-5f);
    #pragma unroll
    for (int i = 0; i < 4; ++i) {
        int d = threadIdx.x + i * 256;
        out[row * DMODEL + d] = (x[i] - mean) * rstd * gamma[d] + beta[d];
    }
}

extern "C" void kernel_launch(void* const* d_in, const int* in_sizes, int n_in,
                              void* d_out, int out_size, void* d_ws, size_t ws_size,
                              hipStream_t stream) {
    const float* inQ  = (const float*)d_in[0];
    const float* inK  = (const float*)d_in[1];
    const float* inV  = (const float*)d_in[2];
    const float* WQ   = (const float*)d_in[3];
    const float* WK   = (const float*)d_in[4];
    const float* WV   = (const float*)d_in[5];
    const float* WF   = (const float*)d_in[6];
    const float* gamma= (const float*)d_in[7];
    const float* beta = (const float*)d_in[8];
    float* outf = (float*)d_out;

    // d_out scratch: bf16 Q at [0,32MB), bf16 K/ctx at [32,64MB)
    ushort* Qb  = (ushort*)d_out;
    ushort* KCb = (ushort*)d_out + (size_t)NROWS * DMODEL;

    // d_ws layout (peak 13.31MB < proven 13.6MB):
    const size_t MB = 1024ull * 1024ull;
    char* w = (char*)d_ws;
    ushort* Vb  = (ushort*)w;                 // [4096][1024] bf16, 8MB; later O_b slot
    ushort* Wt  = (ushort*)(w + 8 * MB);      // 2MB weight^T slot (WQ->WK->WV->WF)
    float* si    = (float*)(w + 10 * MB);     // [4][16][4096] f32, 1MB
    float* soCsk = si + 4 * NHEAD * S_LEN;    // 1MB: csk (dots2)
    float* css   = soCsk + 4 * NHEAD * S_LEN; // 1MB: css -> smw (softmax in-place)
    float* Qsum  = css + 4 * NHEAD * S_LEN;   // 4 sum buffers x [4][16][64] = 64KB
    float* Ksum  = Qsum + 4 * NHEAD * 64;
    float* QsI   = Ksum + 4 * NHEAD * 64;
    float* KsO   = QsI  + 4 * NHEAD * 64;
    float* kvb   = KsO  + 4 * NHEAD * 64;     // [16][64][64] f32, 256KB (per-batch)
    size_t sumZeroBytes = 4 * 4 * NHEAD * 64 * sizeof(float);   // 64KB
    size_t kvZeroBytes  = (size_t)NHEAD * 4096 * sizeof(float); // 256KB

    dim3 tb(32, 8);
    dim3 tg(32, 32);
    dim3 ggFull(DMODEL / 128, NROWS / 128);   // (8, 128)
    dim3 ggBat(DMODEL / 128, BROWS / 128);    // (8, 32)

    // zero Qsum/Ksum/QsI/KsO before gemm epilogue atomics
    hipMemsetAsync(Qsum, 0, sumZeroBytes, stream);

    // Phase 1: Q and K projections (full batch) into d_out; epilogue colsums
    transpose_k<<<tg, tb, 0, stream>>>(WQ, Wt);
    gemm128<1><<<ggFull, 256, 0, stream>>>(inQ, 0, Wt, Qb, 1, Qsum);
    transpose_k<<<tg, tb, 0, stream>>>(WK, Wt);
    gemm128<1><<<ggFull, 256, 0, stream>>>(inK, 0, Wt, KCb, 1, Ksum);
    transpose_k<<<tg, tb, 0, stream>>>(WV, Wt);   // WVt stays through P2

    // Stats: fused dots1(+colsum2), dots2, softmax — all 4 batches per launch
    dots1_k<<<dim3(NHEAD, 32, 4), 256, 0, stream>>>(Qb, KCb, Qsum, Ksum, si, QsI, KsO);
    dots_k<<<dim3(NHEAD, 32, 4), 256, 0, stream>>>(Qb, KCb, KsO, QsI, soCsk, css, 0);
    softmax_k<<<dim3(NHEAD, 4), 256, 0, stream>>>(css, css);

    // Phase 2: per-batch V projection + kv + ctx (ctx_b overwrites dead K_b slice)
    for (int b = 0; b < 4; ++b) {
        size_t rowOff = (size_t)b * BROWS * DMODEL;
        size_t statOff = (size_t)b * NHEAD * S_LEN;
        const ushort* Qs = Qb + rowOff;
        ushort* Ks = KCb + rowOff;
        gemm128<1><<<ggBat, 256, 0, stream>>>(inV, rowOff, Wt, Vb, 0, nullptr);
        hipMemsetAsync(kvb, 0, kvZeroBytes, stream);
        kv_k<<<dim3(NHEAD, KV_SPLIT), 256, 0, stream>>>(Ks, Vb, css + statOff, kvb);
        ctx_k<<<dim3(NHEAD, 16), 256, 0, stream>>>(Qs, kvb, si + statOff, soCsk + statOff, Ks);
    }

    // Phase 3: output projection + LayerNorm (fp32 out)
    transpose_k<<<tg, tb, 0, stream>>>(WF, Wt);   // WVt dead now
    for (int b = 0; b < 4; ++b) {
        size_t rowOff = (size_t)b * BROWS * DMODEL;
        gemm128<0><<<ggBat, 256, 0, stream>>>(KCb + rowOff, 0, Wt, Vb, 0, nullptr);
        ln_k<<<BROWS, 256, 0, stream>>>(Vb, inQ + rowOff, gamma, beta, outf + rowOff);
    }
}

// Round 7
// 919.985 us; speedup vs baseline: 1.1127x; 1.1093x over previous
//
#include <hip/hip_runtime.h>
#include <hip/hip_bf16.h>

// FlowAttention: B=4 S=4096 D=1024 H=16 dk=dv=64. Inputs/outputs fp32.
// Round-12: unbundle R4. R3's gemm structure (93us measured: fp32-A via gld_lds,
// BK=64, 48KB LDS, 2 barriers, cvt at fragment read) was regressed by R4's BK=32
// and never restored; R5/R6 pipelining attempts lost to it (121/148us — guide
// Common-mistake #5 reproduced). This round = R3 gemm body verbatim + the R4-R6
// proven keeps (XCD swizzle FETCH 264->49MB, epilogue colsum, fused dots1,
// swizzled kv/ctx). No other changes.
// Phase order (race-audited, unchanged):
//   memset sums; P1: Q->dout[0,32), K->dout[32,64) (epilogue colsums); WV^T stays
//   stats: dots1_k, dots2(dots_k), softmax(in-place)
//   P2 per b: V_b->ws (AF32 gemm); memset kvb; kv_k; ctx_b overwrites dead K_b
//   WF^T; P3 per b: O_b = ctx_b@Wfc -> ws slot; LN -> dout fp32 rows of b
#define S_LEN 4096
#define DMODEL 1024
#define NHEAD 16
#define NROWS 16384      // B*S
#define BROWS 4096       // rows per batch
#define KV_SPLIT 16

typedef __bf16 bf16x8 __attribute__((ext_vector_type(8)));
typedef float  f32x4  __attribute__((ext_vector_type(4)));

__device__ __forceinline__ float b2f(ushort u) {
    union { uint i; float f; } c; c.i = ((uint)u) << 16; return c.f;
}
__device__ __forceinline__ float blo(uint u) {
    union { uint i; float f; } c; c.i = u << 16; return c.f;
}
__device__ __forceinline__ float bhi(uint u) {
    union { uint i; float f; } c; c.i = u & 0xFFFF0000u; return c.f;
}
__device__ __forceinline__ ushort f2b(float f) {
    union { uint i; float f; } c; c.f = f;
    uint r = c.i + 0x7FFF + ((c.i >> 16) & 1);   // round-to-nearest-even
    return (ushort)(r >> 16);
}
__device__ __forceinline__ float sigmoidf_(float x) {
    return 1.f / (1.f + __expf(-x));
}

// async 16B global->LDS DMA. Dest must be thread-linear (base + tid*16).
__device__ __forceinline__ void gld_lds16(void* lds, const void* g) {
    __builtin_amdgcn_global_load_lds(
        (const __attribute__((address_space(1))) uint*)g,
        (__attribute__((address_space(3))) uint*)lds, 16, 0, 0);
}

// ---------------- transpose 1024x1024: out[n][k] = bf16(in[k][n]), in fp32 ------
__global__ void transpose_k(const float* __restrict__ in, ushort* __restrict__ out) {
    __shared__ ushort tile[32][33];
    int x = blockIdx.x * 32 + threadIdx.x;
    int y0 = blockIdx.y * 32;
    for (int i = threadIdx.y; i < 32; i += 8)
        tile[i][threadIdx.x] = f2b(in[(size_t)(y0 + i) * DMODEL + x]);
    __syncthreads();
    int xo = blockIdx.y * 32 + threadIdx.x;
    int yo0 = blockIdx.x * 32;
    for (int i = threadIdx.y; i < 32; i += 8)
        out[(size_t)(yo0 + i) * DMODEL + xo] = tile[threadIdx.x][i];
}

// ---------------- MFMA GEMM: C[M,1024] = act(A[M,1024] @ Bt^T) ------------------
// R3 structure: 128x128 tile, 4 waves 2x2, each wave 64x64 via 4x4 mfma
// 16x16x32 bf16, BK=64, 2 barriers/iter, all staging via gld_lds.
// LDS: B bf16 [128][64] @0 (16KB); A: AF32 ? two f32 [128][32] halves @16K/@32K
// (48KB total) : bf16 [128][64] @16K (32KB total).
// Swizzle byte_in_row ^= (row&7)<<4: inverse on GLOBAL source, applied on LDS
// read; DMA dest linear (rule #21). AF32 fragment read converts f32->bf16 inline.
// XCD swizzle: lid=(bid&7)*(nwg/8)+bid/8 (nwg divisible by 8; gridDim.x==8).
// csum != nullptr: epilogue per-column sums of stored output into csum[b][h][64].
template<int AF32>
__global__ __launch_bounds__(256) void gemm128(const void* __restrict__ A, size_t aoff,
                                               const ushort* __restrict__ Bt,
                                               ushort* __restrict__ C, int act,
                                               float* __restrict__ csum) {
    constexpr int SMEM_BYTES = AF32 ? 49152 : 32768;
    __shared__ __align__(16) char smem[SMEM_BYTES];
    char* smA = smem + 16384;

    int nwg = (int)(gridDim.x * gridDim.y);
    int bid = (int)(blockIdx.y * gridDim.x + blockIdx.x);
    int lid = (bid & 7) * (nwg >> 3) + (bid >> 3);
    int n0 = (lid & 7) * 128;                     // gridDim.x == 8
    int m0 = (lid >> 3) * 128;

    int t = threadIdx.x;
    int lane = t & 63, wave = t >> 6;
    int wm = (wave >> 1) * 64, wn = (wave & 1) * 64;
    int fr = lane & 15;            // frag row (A) / col (B)
    int kq = (lane >> 4) * 8;      // k offset within 32-step

    const float*  Af = (const float*)A + aoff;
    const ushort* Ab = (const ushort*)A + aoff;

    // staging descriptors (k0-invariant): round r covers LDS bytes
    // [r*4096 + t*16, +16) of a 16KB tile.
    int ldsOff[4], rowOf[4], bcB[4];
    #pragma unroll
    for (int r = 0; r < 4; ++r) {
        int o = t * 16 + r * 4096;
        int row = o >> 7;
        ldsOff[r] = o;
        rowOf[r] = row;
        bcB[r] = (o & 127) ^ ((row & 7) << 4);
    }

    f32x4 acc[4][4];
    #pragma unroll
    for (int i = 0; i < 4; ++i)
        #pragma unroll
        for (int j = 0; j < 4; ++j) acc[i][j] = (f32x4){0.f, 0.f, 0.f, 0.f};

    for (int k0 = 0; k0 < DMODEL; k0 += 64) {
        __syncthreads();   // prev iteration's LDS reads done before overwrite
        // B tile [128][64] bf16: 4 DMA rounds
        #pragma unroll
        for (int r = 0; r < 4; ++r)
            gld_lds16(smem + ldsOff[r],
                      Bt + (size_t)(n0 + rowOf[r]) * DMODEL + k0 + (bcB[r] >> 1));
        if (AF32) {
            // two fp32 half tiles [128][32], rounds share (row, bc) geometry
            #pragma unroll
            for (int hh = 0; hh < 2; ++hh)
                #pragma unroll
                for (int r = 0; r < 4; ++r)
                    gld_lds16(smA + hh * 16384 + ldsOff[r],
                              Af + (size_t)(m0 + rowOf[r]) * DMODEL + k0 + hh * 32 + (bcB[r] >> 2));
        } else {
            #pragma unroll
            for (int r = 0; r < 4; ++r)
                gld_lds16(smA + ldsOff[r],
                          Ab + (size_t)(m0 + rowOf[r]) * DMODEL + k0 + (bcB[r] >> 1));
        }
        __syncthreads();   // compiler emits vmcnt(0) drain before barrier

        #pragma unroll
        for (int h = 0; h < 2; ++h) {
            bf16x8 av[4], bv[4];
            #pragma unroll
            for (int i = 0; i < 4; ++i) {
                int row = wm + i * 16 + fr;
                int swz = (row & 7) << 4;
                if (AF32) {
                    const char* Ah = smA + h * 16384;
                    int o1 = ((row << 7) + (kq << 2)) ^ swz;
                    int o2 = ((row << 7) + ((kq + 4) << 2)) ^ swz;
                    float4 q0 = *(const float4*)(Ah + o1);
                    float4 q1 = *(const float4*)(Ah + o2);
                    bf16x8 a;
                    a[0] = (__bf16)q0.x; a[1] = (__bf16)q0.y;
                    a[2] = (__bf16)q0.z; a[3] = (__bf16)q0.w;
                    a[4] = (__bf16)q1.x; a[5] = (__bf16)q1.y;
                    a[6] = (__bf16)q1.z; a[7] = (__bf16)q1.w;
                    av[i] = a;
                } else {
                    int k = h * 32 + kq;
                    int o = ((row << 7) + (k << 1)) ^ swz;
                    av[i] = *(const bf16x8*)(smA + o);
                }
            }
            #pragma unroll
            for (int j = 0; j < 4; ++j) {
                int nrow = wn + j * 16 + fr;
                int k = h * 32 + kq;
                int o = ((nrow << 7) + (k << 1)) ^ ((nrow & 7) << 4);
                bv[j] = *(const bf16x8*)(smem + o);
            }
            #pragma unroll
            for (int i = 0; i < 4; ++i)
                #pragma unroll
                for (int j = 0; j < 4; ++j)
                    acc[i][j] = __builtin_amdgcn_mfma_f32_16x16x32_bf16(av[i], bv[j], acc[i][j], 0, 0, 0);
        }
    }

    int rbase = (lane >> 4) * 4;
    int cix = lane & 15;
    float colacc[4] = {0.f, 0.f, 0.f, 0.f};
    #pragma unroll
    for (int i = 0; i < 4; ++i)
        #pragma unroll
        for (int j = 0; j < 4; ++j) {
            int col = n0 + wn + j * 16 + cix;
            #pragma unroll
            for (int r = 0; r < 4; ++r) {
                int row = m0 + wm + i * 16 + rbase + r;
                float v = acc[i][j][r];
                if (act) v = sigmoidf_(v);
                ushort ub = f2b(v);
                C[(size_t)row * DMODEL + col] = ub;
                if (csum) colacc[j] += b2f(ub);
            }
        }
    if (csum) {
        __syncthreads();                // all LDS frag reads done; reuse smem
        float* cred = (float*)smem;     // [2][128]
        cred[t] = 0.f;
        __syncthreads();
        #pragma unroll
        for (int j = 0; j < 4; ++j) {
            float s = colacc[j];
            s += __shfl_xor(s, 16);
            s += __shfl_xor(s, 32);     // sum over wave's 64 rows
            if (lane < 16) cred[(wm >> 6) * 128 + wn + j * 16 + lane] = s;
        }
        __syncthreads();
        if (t < 128) {
            float tot = cred[t] + cred[128 + t];
            int col = n0 + t;
            int b = m0 >> 12;           // 4096 rows per batch
            atomicAdd(&csum[((size_t)b * NHEAD + (col >> 6)) * 64 + (col & 63)], tot);
        }
    }
}

// ---- fused dots1 + weighted colsum2, batched over b (z) ----
// dq = Q[s]·Ksum -> si = 1/dq (stored); dk = K[s]·Qsum -> so = 1/dk (not stored)
// QsI[d] += sum_s Q[s,d]*si[s] ; KsO[d] += sum_s K[s,d]*so[s]  (atomic per wave-lane)
__global__ void dots1_k(const ushort* __restrict__ Q, const ushort* __restrict__ K,
                        const float* __restrict__ Qsum, const float* __restrict__ Ksum,
                        float* __restrict__ si_out, float* __restrict__ qsi,
                        float* __restrict__ kso) {
    int h = blockIdx.x, b = blockIdx.z;
    int lane = threadIdx.x & 63, wv = threadIdx.x >> 6;
    const ushort* qp = Q + (size_t)b * BROWS * DMODEL + h * 64 + lane;
    const ushort* kp = K + (size_t)b * BROWS * DMODEL + h * 64 + lane;
    float vql = Ksum[((size_t)b * NHEAD + h) * 64 + lane];
    float vkl = Qsum[((size_t)b * NHEAD + h) * 64 + lane];
    float* sip = si_out + ((size_t)b * NHEAD + h) * S_LEN;
    int s0 = blockIdx.y * 128 + wv * 32;
    float aq = 0.f, ak = 0.f;
    for (int i = 0; i < 32; ++i) {
        int s = s0 + i;
        float qv = b2f(qp[(size_t)s * DMODEL]);
        float kv = b2f(kp[(size_t)s * DMODEL]);
        float dq = qv * vql, dk = kv * vkl;
        #pragma unroll
        for (int off = 32; off; off >>= 1) {
            dq += __shfl_xor(dq, off);
            dk += __shfl_xor(dk, off);
        }
        float si_ = 1.f / dq, so_ = 1.f / dk;
        if (lane == 0) sip[s] = si_;
        aq += qv * si_;
        ak += kv * so_;
    }
    atomicAdd(&qsi[((size_t)b * NHEAD + h) * 64 + lane], aq);
    atomicAdd(&kso[((size_t)b * NHEAD + h) * 64 + lane], ak);
}

// ---- per-s dots with a per-head 64-vector, batched over b (z) ----
__global__ void dots_k(const ushort* __restrict__ Q, const ushort* __restrict__ K,
                       const float* __restrict__ vq, const float* __restrict__ vk,
                       float* __restrict__ outq, float* __restrict__ outk, int invert) {
    int h = blockIdx.x;
    int b = blockIdx.z;
    const ushort* Qb = Q + (size_t)b * BROWS * DMODEL;
    const ushort* Kb = K + (size_t)b * BROWS * DMODEL;
    const float* vqb = vq + (size_t)b * NHEAD * 64;
    const float* vkb = vk + (size_t)b * NHEAD * 64;
    float* oq = outq + (size_t)b * NHEAD * S_LEN;
    float* ok = outk + (size_t)b * NHEAD * S_LEN;
    int lane = threadIdx.x & 63, wv = threadIdx.x >> 6;
    const ushort* qp = Qb + h * 64 + lane;
    const ushort* kp = Kb + h * 64 + lane;
    float vql = vqb[h * 64 + lane];
    float vkl = vkb[h * 64 + lane];
    int s0 = blockIdx.y * 128 + wv * 32;
    for (int i = 0; i < 32; ++i) {
        int s = s0 + i;
        float dq = b2f(qp[(size_t)s * DMODEL]) * vql;
        float dk = b2f(kp[(size_t)s * DMODEL]) * vkl;
        #pragma unroll
        for (int off = 32; off; off >>= 1) {
            dq += __shfl_xor(dq, off);
            dk += __shfl_xor(dk, off);
        }
        if (lane == 0) {
            oq[(size_t)h * S_LEN + s] = invert ? 1.f / dq : dq;
            ok[(size_t)h * S_LEN + s] = invert ? 1.f / dk : dk;
        }
    }
}

// ---- softmax over S per head, batched over b (y); safe in-place (w may == x) ----
__global__ void softmax_k(const float* x, float* w) {
    int h = blockIdx.x;
    int b = blockIdx.y;
    const float* xp = x + ((size_t)b * NHEAD + h) * S_LEN;
    float* wp = w + ((size_t)b * NHEAD + h) * S_LEN;
    float loc[16];
    float mx = -1e30f;
    #pragma unroll
    for (int i = 0; i < 16; ++i) { loc[i] = xp[threadIdx.x + i * 256]; mx = fmaxf(mx, loc[i]); }
    __shared__ float red[256];
    red[threadIdx.x] = mx; __syncthreads();
    for (int st = 128; st; st >>= 1) {
        if (threadIdx.x < st) red[threadIdx.x] = fmaxf(red[threadIdx.x], red[threadIdx.x + st]);
        __syncthreads();
    }
    mx = red[0]; __syncthreads();
    float sm = 0.f;
    #pragma unroll
    for (int i = 0; i < 16; ++i) { loc[i] = __expf(loc[i] - mx); sm += loc[i]; }
    red[threadIdx.x] = sm; __syncthreads();
    for (int st = 128; st; st >>= 1) {
        if (threadIdx.x < st) red[threadIdx.x] += red[threadIdx.x + st];
        __syncthreads();
    }
    float inv = 1.f / red[0];
    #pragma unroll
    for (int i = 0; i < 16; ++i)
        wp[threadIdx.x + i * 256] = loc[i] * inv;
}

// ---- kv[h,k,v] = sum_s (K[s,k]*w[h,s]) * V[s,v], one batch (split-S atomics) ----
// XCD remap: same-s blocks (all 16 h) co-locate on one XCD (K rows fetched once/XCD).
__global__ __launch_bounds__(256) void kv_k(const ushort* __restrict__ K,
                                            const ushort* __restrict__ V,
                                            const float* __restrict__ w,
                                            float* __restrict__ kv) {
    int bid = (int)(blockIdx.y * gridDim.x + blockIdx.x);   // gridDim = (16, 16)
    int lid = (bid & 7) * 32 + (bid >> 3);
    int h = lid & 15;
    int sy = lid >> 4;
    __shared__ __align__(16) float  KwS[64 * 64];
    __shared__ __align__(16) ushort Vt[64 * 64];
    int t = threadIdx.x;
    int kk = (t & 31) * 2;          // k pair
    int v0 = (t >> 5) * 8;          // v oct
    float acc[2][8];
    #pragma unroll
    for (int i = 0; i < 2; ++i)
        #pragma unroll
        for (int j = 0; j < 8; ++j) acc[i][j] = 0.f;
    int sl_s = t >> 2, q = t & 3;   // staging: row, quarter
    int sBase = sy * (S_LEN / KV_SPLIT);
    for (int t0 = 0; t0 < S_LEN / KV_SPLIT; t0 += 64) {
        __syncthreads();
        // V tile: 8KB linear, 2 DMA rounds
        #pragma unroll
        for (int r = 0; r < 2; ++r) {
            int o = t * 16 + r * 4096;
            int row = o >> 7;
            gld_lds16((char*)Vt + o,
                      V + (size_t)(sBase + t0 + row) * DMODEL + h * 64 + ((o & 127) >> 1));
        }
        // K tile: reg-staged f32 * w, swizzled
        {
            int s = sBase + t0 + sl_s;
            float ws = w[(size_t)h * S_LEN + s];
            const ushort* kp = K + (size_t)s * DMODEL + h * 64 + q * 16;
            uint4 ka = *(const uint4*)kp;
            uint4 kb = *(const uint4*)(kp + 8);
            int swz = (sl_s & 7) << 4;
            char* base = (char*)KwS + sl_s * 256;
            f32x4 c0 = { blo(ka.x) * ws, bhi(ka.x) * ws, blo(ka.y) * ws, bhi(ka.y) * ws };
            f32x4 c1 = { blo(ka.z) * ws, bhi(ka.z) * ws, blo(ka.w) * ws, bhi(ka.w) * ws };
            f32x4 c2 = { blo(kb.x) * ws, bhi(kb.x) * ws, blo(kb.y) * ws, bhi(kb.y) * ws };
            f32x4 c3 = { blo(kb.z) * ws, bhi(kb.z) * ws, blo(kb.w) * ws, bhi(kb.w) * ws };
            *(f32x4*)(base + ((q * 64 +  0) ^ swz)) = c0;
            *(f32x4*)(base + ((q * 64 + 16) ^ swz)) = c1;
            *(f32x4*)(base + ((q * 64 + 32) ^ swz)) = c2;
            *(f32x4*)(base + ((q * 64 + 48) ^ swz)) = c3;
        }
        __syncthreads();
        #pragma unroll 2
        for (int sl = 0; sl < 64; ++sl) {
            int swz = (sl & 7) << 4;
            float2 kf = *(const float2*)((const char*)KwS + sl * 256 + ((kk * 4) ^ swz));
            uint4 vv = *(const uint4*)((const char*)Vt + sl * 128 + v0 * 2);
            float vf0 = blo(vv.x), vf1 = bhi(vv.x), vf2 = blo(vv.y), vf3 = bhi(vv.y);
            float vf4 = blo(vv.z), vf5 = bhi(vv.z), vf6 = blo(vv.w), vf7 = bhi(vv.w);
            acc[0][0] += kf.x * vf0; acc[0][1] += kf.x * vf1;
            acc[0][2] += kf.x * vf2; acc[0][3] += kf.x * vf3;
            acc[0][4] += kf.x * vf4; acc[0][5] += kf.x * vf5;
            acc[0][6] += kf.x * vf6; acc[0][7] += kf.x * vf7;
            acc[1][0] += kf.y * vf0; acc[1][1] += kf.y * vf1;
            acc[1][2] += kf.y * vf2; acc[1][3] += kf.y * vf3;
            acc[1][4] += kf.y * vf4; acc[1][5] += kf.y * vf5;
            acc[1][6] += kf.y * vf6; acc[1][7] += kf.y * vf7;
        }
    }
    float* kvp = kv + (size_t)h * 4096;
    #pragma unroll
    for (int i = 0; i < 2; ++i)
        #pragma unroll
        for (int j = 0; j < 8; ++j)
            atomicAdd(&kvp[(kk + i) * 64 + v0 + j], acc[i][j]);
}

// ---- ctx[s,h*64+v] = sig(csink[h,s])*si[h,s]*sum_k Q[s,h*64+k]*kv[h,k,v] ----
__global__ __launch_bounds__(256) void ctx_k(const ushort* __restrict__ Q,
                                             const float* __restrict__ kv,
                                             const float* __restrict__ si,
                                             const float* __restrict__ csink,
                                             ushort* __restrict__ ctx) {
    int bid = (int)(blockIdx.y * gridDim.x + blockIdx.x);   // gridDim = (16, 16)
    int lid = (bid & 7) * 32 + (bid >> 3);
    int h = lid & 15;
    int sBlock = (lid >> 4) * 256;
    __shared__ __align__(16) float  kvf[64 * 64];   // [k][v] linear
    __shared__ __align__(16) ushort Qt[64 * 64];    // [s][k] source-preswizzled
    int t = threadIdx.x;
    {
        const float* kp = kv + (size_t)h * 4096;
        #pragma unroll
        for (int i = 0; i < 4; ++i) {
            int idx = t * 4 + i * 1024;
            *(f32x4*)&kvf[idx] = *(const f32x4*)&kp[idx];
        }
    }
    int spair = t >> 3;            // 0..31
    int v0 = (t & 7) * 8;
    for (int tile = 0; tile < 4; ++tile) {
        __syncthreads();           // prev-tile reads done (also covers kvf stage)
        int sT = sBlock + tile * 64;
        #pragma unroll
        for (int r = 0; r < 2; ++r) {
            int o = t * 16 + r * 4096;
            int row = o >> 7;
            int cb = (o & 127) ^ ((row & 7) << 4);
            gld_lds16((char*)Qt + o, Q + (size_t)(sT + row) * DMODEL + h * 64 + (cb >> 1));
        }
        __syncthreads();
        int s0 = spair * 2, s1 = s0 + 1;
        int swz0 = (s0 & 7) << 4, swz1 = (s1 & 7) << 4;
        float acc0[8], acc1[8];
        #pragma unroll
        for (int j = 0; j < 8; ++j) { acc0[j] = 0.f; acc1[j] = 0.f; }
        #pragma unroll 4
        for (int k = 0; k < 64; k += 4) {
            union { ushort4 v; ushort u[4]; } qa, qb;
            qa.v = *(const ushort4*)((const char*)Qt + s0 * 128 + ((k * 2) ^ swz0));
            qb.v = *(const ushort4*)((const char*)Qt + s1 * 128 + ((k * 2) ^ swz1));
            const char* rbase = (const char*)kvf + k * 256 + v0 * 4;
            #pragma unroll
            for (int kk2 = 0; kk2 < 4; ++kk2) {
                f32x4 r0 = *(const f32x4*)(rbase + kk2 * 256);
                f32x4 r1 = *(const f32x4*)(rbase + kk2 * 256 + 16);
                float qaf = b2f(qa.u[kk2]);
                float qbf = b2f(qb.u[kk2]);
                #pragma unroll
                for (int j = 0; j < 4; ++j) {
                    acc0[j]     += qaf * r0[j];
                    acc0[4 + j] += qaf * r1[j];
                    acc1[j]     += qbf * r0[j];
                    acc1[4 + j] += qbf * r1[j];
                }
            }
        }
        int gs0 = sT + s0, gs1 = sT + s1;
        float sc0 = si[(size_t)h * S_LEN + gs0] * sigmoidf_(csink[(size_t)h * S_LEN + gs0]);
        float sc1 = si[(size_t)h * S_LEN + gs1] * sigmoidf_(csink[(size_t)h * S_LEN + gs1]);
        union { ushort u[8]; uint4 v; } o0, o1;
        #pragma unroll
        for (int j = 0; j < 8; ++j) {
            o0.u[j] = f2b(acc0[j] * sc0);
            o1.u[j] = f2b(acc1[j] * sc1);
        }
        *(uint4*)(ctx + (size_t)gs0 * DMODEL + h * 64 + v0) = o0.v;
        *(uint4*)(ctx + (size_t)gs1 * DMODEL + h * 64 + v0) = o1.v;
    }
}

// ---- LayerNorm(y_bf16 + residual_f32) * gamma + beta -> fp32 out (per-row) ----
__global__ void ln_k(const ushort* __restrict__ y, const float* __restrict__ res,
                     const float* __restrict__ gamma, const float* __restrict__ beta,
                     float* __restrict__ out) {
    size_t row = blockIdx.x;
    const ushort* yp = y + row * DMODEL;
    const float* rp = res + row * DMODEL;
    float x[4];
    float s = 0.f, s2 = 0.f;
    #pragma unroll
    for (int i = 0; i < 4; ++i) {
        int d = threadIdx.x + i * 256;
        x[i] = b2f(yp[d]) + rp[d];
        s += x[i]; s2 += x[i] * x[i];
    }
    __shared__ float r1[256], r2[256];
    r1[threadIdx.x] = s; r2[threadIdx.x] = s2;
    __syncthreads();
    for (int st = 128; st; st >>= 1) {
        if (threadIdx.x < st) { r1[threadIdx.x] += r1[threadIdx.x + st]; r2[threadIdx.x] += r2[threadIdx.x + st]; }
        __syncthreads();
    }
    float mean = r1[0] * (1.f / DMODEL);
    float var = r2[0] * (1.f / DMODEL) - mean * mean;
    float rstd = rsqrtf(var + 1e-5f);
    #pragma unroll
    for (int i = 0; i < 4; ++i) {
        int d = threadIdx.x + i * 256;
        out[row * DMODEL + d] = (x[i] - mean) * rstd * gamma[d] + beta[d];
    }
}

extern "C" void kernel_launch(void* const* d_in, const int* in_sizes, int n_in,
                              void* d_out, int out_size, void* d_ws, size_t ws_size,
                              hipStream_t stream) {
    const float* inQ  = (const float*)d_in[0];
    const float* inK  = (const float*)d_in[1];
    const float* inV  = (const float*)d_in[2];
    const float* WQ   = (const float*)d_in[3];
    const float* WK   = (const float*)d_in[4];
    const float* WV   = (const float*)d_in[5];
    const float* WF   = (const float*)d_in[6];
    const float* gamma= (const float*)d_in[7];
    const float* beta = (const float*)d_in[8];
    float* outf = (float*)d_out;

    // d_out scratch: bf16 Q at [0,32MB), bf16 K/ctx at [32,64MB)
    ushort* Qb  = (ushort*)d_out;
    ushort* KCb = (ushort*)d_out + (size_t)NROWS * DMODEL;

    // d_ws layout (peak 13.31MB < proven 13.6MB):
    const size_t MB = 1024ull * 1024ull;
    char* w = (char*)d_ws;
    ushort* Vb  = (ushort*)w;                 // [4096][1024] bf16, 8MB; later O_b slot
    ushort* Wt  = (ushort*)(w + 8 * MB);      // 2MB weight^T slot (WQ->WK->WV->WF)
    float* si    = (float*)(w + 10 * MB);     // [4][16][4096] f32, 1MB
    float* soCsk = si + 4 * NHEAD * S_LEN;    // 1MB: csk (dots2)
    float* css   = soCsk + 4 * NHEAD * S_LEN; // 1MB: css -> smw (softmax in-place)
    float* Qsum  = css + 4 * NHEAD * S_LEN;   // 4 sum buffers x [4][16][64] = 64KB
    float* Ksum  = Qsum + 4 * NHEAD * 64;
    float* QsI   = Ksum + 4 * NHEAD * 64;
    float* KsO   = QsI  + 4 * NHEAD * 64;
    float* kvb   = KsO  + 4 * NHEAD * 64;     // [16][64][64] f32, 256KB (per-batch)
    size_t sumZeroBytes = 4 * 4 * NHEAD * 64 * sizeof(float);   // 64KB
    size_t kvZeroBytes  = (size_t)NHEAD * 4096 * sizeof(float); // 256KB

    dim3 tb(32, 8);
    dim3 tg(32, 32);
    dim3 ggFull(DMODEL / 128, NROWS / 128);   // (8, 128)
    dim3 ggBat(DMODEL / 128, BROWS / 128);    // (8, 32)

    // zero Qsum/Ksum/QsI/KsO before gemm epilogue atomics
    hipMemsetAsync(Qsum, 0, sumZeroBytes, stream);

    // Phase 1: Q and K projections (full batch) into d_out; epilogue colsums
    transpose_k<<<tg, tb, 0, stream>>>(WQ, Wt);
    gemm128<1><<<ggFull, 256, 0, stream>>>(inQ, 0, Wt, Qb, 1, Qsum);
    transpose_k<<<tg, tb, 0, stream>>>(WK, Wt);
    gemm128<1><<<ggFull, 256, 0, stream>>>(inK, 0, Wt, KCb, 1, Ksum);
    transpose_k<<<tg, tb, 0, stream>>>(WV, Wt);   // WVt stays through P2

    // Stats: fused dots1(+colsum2), dots2, softmax — all 4 batches per launch
    dots1_k<<<dim3(NHEAD, 32, 4), 256, 0, stream>>>(Qb, KCb, Qsum, Ksum, si, QsI, KsO);
    dots_k<<<dim3(NHEAD, 32, 4), 256, 0, stream>>>(Qb, KCb, KsO, QsI, soCsk, css, 0);
    softmax_k<<<dim3(NHEAD, 4), 256, 0, stream>>>(css, css);

    // Phase 2: per-batch V projection + kv + ctx (ctx_b overwrites dead K_b slice)
    for (int b = 0; b < 4; ++b) {
        size_t rowOff = (size_t)b * BROWS * DMODEL;
        size_t statOff = (size_t)b * NHEAD * S_LEN;
        const ushort* Qs = Qb + rowOff;
        ushort* Ks = KCb + rowOff;
        gemm128<1><<<ggBat, 256, 0, stream>>>(inV, rowOff, Wt, Vb, 0, nullptr);
        hipMemsetAsync(kvb, 0, kvZeroBytes, stream);
        kv_k<<<dim3(NHEAD, KV_SPLIT), 256, 0, stream>>>(Ks, Vb, css + statOff, kvb);
        ctx_k<<<dim3(NHEAD, 16), 256, 0, stream>>>(Qs, kvb, si + statOff, soCsk + statOff, Ks);
    }

    // Phase 3: output projection + LayerNorm (fp32 out)
    transpose_k<<<tg, tb, 0, stream>>>(WF, Wt);   // WVt dead now
    for (int b = 0; b < 4; ++b) {
        size_t rowOff = (size_t)b * BROWS * DMODEL;
        gemm128<0><<<ggBat, 256, 0, stream>>>(KCb + rowOff, 0, Wt, Vb, 0, nullptr);
        ln_k<<<BROWS, 256, 0, stream>>>(Vb, inQ + rowOff, gamma, beta, outf + rowOff);
    }
}